// Round 3
// baseline (4009.855 us; speedup 1.0000x reference)
//
#include <hip/hip_runtime.h>
#include <hip/hip_bf16.h>

#define Bb 64
#define Tt 256
#define Ii 256
#define Hh 512
#define Cc 1000
#define RD 4  // xg ring depth (steps)

typedef float f4 __attribute__((ext_vector_type(4)));
typedef short s8 __attribute__((ext_vector_type(8)));
typedef unsigned long long u64;

__device__ __forceinline__ unsigned short f2bf(float f) {
  union { float f; unsigned u; } v; v.f = f;
  return (unsigned short)((v.u + 0x7FFFu + ((v.u >> 16) & 1u)) >> 16);
}
__device__ __forceinline__ float sigf(float x) {
  return __builtin_amdgcn_rcpf(1.f + __expf(-x));
}
__device__ __forceinline__ float tanhs(float x) {
  float ax = fabsf(x);
  float e = __expf(-2.f * ax);
  float r = (1.f - e) * __builtin_amdgcn_rcpf(1.f + e);
  return copysignf(r, x);
}

struct P2 {
  const float* x;
  const float* Whh[3]; const float* Wih[3];
  const float* bih[3]; const float* bhh[3];
  unsigned short* y[3];
  float* ring;      // [3][16][4][RD][64 lanes][32 floats]
  unsigned* hfl;    // [3][4 waves][16 s] monotonic step counters
  unsigned* xgfl;   // [3][4 waves][16 s]
};

__global__ void zero_flags(unsigned* f) {
  for (int i = threadIdx.x; i < 384; i += 256) f[i] = 0;
}

__global__ void bias_init_kernel(const float* __restrict__ fcb, float* __restrict__ out) {
  int i = blockIdx.x * 256 + threadIdx.x;
  if (i < Bb * Cc) out[i] = fcb[i % Cc];
}

// 96 blocks: bid<48 = recurrent (L=bid/16, s=bid%16, 32 h-dims each);
// bid>=48 = xg producer (W_ih@input + bias into ring, up to RD steps ahead).
// Per-wave independent chains: wave w owns batches [16w,16w+16); no barriers in loop.
__launch_bounds__(256, 1)
__global__ void lstm_kernel(P2 p) {
  const int bid = blockIdx.x;
  const int tid = threadIdx.x;
  const int lane = tid & 63;
  const int w = tid >> 6;
  const int q = lane >> 4;
  const int c = lane & 15;
  const bool isrec = bid < 48;
  const int L = isrec ? (bid >> 4) : ((bid - 48) >> 4);
  const int s = isrec ? (bid & 15) : ((bid - 48) & 15);
  const int n0 = s * 32;

  __shared__ unsigned short Wlds[128 * 512];  // 128 KB

  const int K = (!isrec && L == 0) ? Ii : Hh;
  {  // stage weight slice: LDS row r=tau*16+rho -> global gate-row g*512+n0+8*(rho>>2)+tau
    const float* wsrc = isrec ? p.Whh[L] : p.Wih[L];
    const int kd8 = K >> 3;
    for (int idx = tid; idx < 128 * kd8; idx += 256) {
      int r = idx / kd8;
      int kk = (idx - r * kd8) << 3;
      int rho = r & 15, tau = r >> 4;
      int j = (rho & 3) * Hh + n0 + 8 * (rho >> 2) + tau;
      const float* srow = wsrc + (size_t)j * K + kk;
      s8 tv;
#pragma unroll
      for (int e = 0; e < 8; ++e) tv[e] = (short)f2bf(srow[e]);
      int byt = ((r * K + kk) * 2) ^ ((r & 7) << 4);
      *(s8*)((char*)Wlds + byt) = tv;
    }
  }
  __syncthreads();

  const int aswz = (lane & 7) << 4;
  unsigned* myxgfl = p.xgfl + (L * 4 + w) * 16 + s;
  unsigned* hline = p.hfl + (L * 4 + w) * 16;
  float* ringbase = p.ring + (size_t)((L * 16 + s) * 4 + w) * (RD * 2048);

  if (isrec) {
    unsigned short* yl = p.y[L];
    float cst[8];
#pragma unroll
    for (int i = 0; i < 8; ++i) cst[i] = 0.f;

    for (int t = 0; t < Tt; ++t) {
      // 1. wait for xg[t] (producer runs ahead; usually instant)
      while (__hip_atomic_load(myxgfl, __ATOMIC_RELAXED, __HIP_MEMORY_SCOPE_AGENT) <
             (unsigned)(t + 1))
        __builtin_amdgcn_s_sleep(1);
      asm volatile("" ::: "memory");
      // 2. issue acc init loads (LLC, coherent — ring slots are rewritten in-dispatch)
      const u64* sp = (const u64*)(ringbase + (size_t)(t & (RD - 1)) * 2048 + lane * 32);
      f4 acc[8];
#pragma unroll
      for (int tt = 0; tt < 8; ++tt) {
        union { f4 v; u64 u[2]; } cv;
        cv.u[0] = __hip_atomic_load(sp + tt * 2, __ATOMIC_RELAXED, __HIP_MEMORY_SCOPE_AGENT);
        cv.u[1] = __hip_atomic_load(sp + tt * 2 + 1, __ATOMIC_RELAXED, __HIP_MEMORY_SCOPE_AGENT);
        acc[tt] = cv.v;
      }
      if (t > 0) {
        // 3. wait for all 16 same-wave producers of h[t-1]
        bool pass;
        do {
          unsigned v = 0xFFFFFFFFu;
          if (lane < 16)
            v = __hip_atomic_load(hline + lane, __ATOMIC_RELAXED, __HIP_MEMORY_SCOPE_AGENT);
          pass = __all(v >= (unsigned)t);
          if (!pass) __builtin_amdgcn_s_sleep(1);
        } while (!pass);
        asm volatile("" ::: "memory");
        // 4. recurrent GEMM: 8 row-tiles x 16 k-chunks
        const unsigned short* hr = yl + ((size_t)(16 * w + c) * Tt + (t - 1)) * Hh + q * 8;
        s8 hb[16];
#pragma unroll
        for (int kc = 0; kc < 16; ++kc) hb[kc] = *(const s8*)(hr + kc * 32);
#pragma unroll
        for (int tt = 0; tt < 8; ++tt) {
#pragma unroll
          for (int kc = 0; kc < 16; ++kc) {
            int byt = (((tt * 16 + c) * 512 + kc * 32 + q * 8) * 2) ^ aswz;
            s8 wa = *(const s8*)((const char*)Wlds + byt);
            acc[tt] = __builtin_amdgcn_mfma_f32_16x16x32_bf16(wa, hb[kc], acc[tt], 0, 0, 0);
          }
        }
      }
      // 5. pointwise: lane (q,c) owns n' = 8q+tt, gates in acc[tt][0..3] = {i,f,g,o}
      unsigned short hu[8];
#pragma unroll
      for (int tt = 0; tt < 8; ++tt) {
        float ii = sigf(acc[tt][0]), ff = sigf(acc[tt][1]);
        float gg = tanhs(acc[tt][2]), oo = sigf(acc[tt][3]);
        cst[tt] = ff * cst[tt] + ii * gg;
        hu[tt] = f2bf(oo * tanhs(cst[tt]));
      }
      u64 lo = (u64)hu[0] | ((u64)hu[1] << 16) | ((u64)hu[2] << 32) | ((u64)hu[3] << 48);
      u64 hi = (u64)hu[4] | ((u64)hu[5] << 16) | ((u64)hu[6] << 32) | ((u64)hu[7] << 48);
      u64* dst = (u64*)(yl + ((size_t)(16 * w + c) * Tt + t) * Hh + n0 + 8 * q);
      __hip_atomic_store(dst, lo, __ATOMIC_RELAXED, __HIP_MEMORY_SCOPE_AGENT);
      __hip_atomic_store(dst + 1, hi, __ATOMIC_RELAXED, __HIP_MEMORY_SCOPE_AGENT);
      asm volatile("s_waitcnt vmcnt(0)" ::: "memory");  // h acked at LLC
      if (lane == 0)
        __hip_atomic_store(hline + s, (unsigned)(t + 1), __ATOMIC_RELAXED,
                           __HIP_MEMORY_SCOPE_AGENT);
    }
  } else {
    // xg producer: acc = bias; acc += Wih @ input[t]; store ring slot; flag.
    unsigned* guard = p.hfl + (L * 4 + w) * 16 + s;  // consumer progress (ring back-pressure)
    unsigned* lowline = p.hfl + ((L > 0 ? L - 1 : 0) * 4 + w) * 16;
    const unsigned short* ylow = (L > 0) ? p.y[L - 1] : (unsigned short*)0;
    f4 bias[8];
#pragma unroll
    for (int tt = 0; tt < 8; ++tt) {
#pragma unroll
      for (int g = 0; g < 4; ++g) {
        int bi = g * Hh + n0 + 8 * q + tt;
        bias[tt][g] = p.bih[L][bi] + p.bhh[L][bi];
      }
    }
    for (int t = 0; t < Tt; ++t) {
      bool pass;
      do {
        bool mine = true;
        if (L > 0 && lane < 16)
          mine = (__hip_atomic_load(lowline + lane, __ATOMIC_RELAXED,
                                    __HIP_MEMORY_SCOPE_AGENT) >= (unsigned)(t + 1));
        if (lane == 0 && t >= RD)
          mine = mine && (__hip_atomic_load(guard, __ATOMIC_RELAXED,
                                            __HIP_MEMORY_SCOPE_AGENT) >=
                          (unsigned)(t - RD + 1));
        pass = __all(mine);
        if (!pass) __builtin_amdgcn_s_sleep(1);
      } while (!pass);
      asm volatile("" ::: "memory");
      f4 acc[8];
#pragma unroll
      for (int tt = 0; tt < 8; ++tt) acc[tt] = bias[tt];
      if (L == 0) {
        const float* xr = p.x + ((size_t)(16 * w + c) * Tt + t) * Ii + q * 8;
        s8 xb[8];
#pragma unroll
        for (int kc = 0; kc < 8; ++kc) {
          f4 xa = *(const f4*)(xr + kc * 32);
          f4 xc = *(const f4*)(xr + kc * 32 + 4);
          s8 tv;
#pragma unroll
          for (int e = 0; e < 4; ++e) { tv[e] = (short)f2bf(xa[e]); tv[e + 4] = (short)f2bf(xc[e]); }
          xb[kc] = tv;
        }
#pragma unroll
        for (int tt = 0; tt < 8; ++tt) {
#pragma unroll
          for (int kc = 0; kc < 8; ++kc) {
            int byt = (((tt * 16 + c) * 256 + kc * 32 + q * 8) * 2) ^ aswz;
            s8 wa = *(const s8*)((const char*)Wlds + byt);
            acc[tt] = __builtin_amdgcn_mfma_f32_16x16x32_bf16(wa, xb[kc], acc[tt], 0, 0, 0);
          }
        }
      } else {
        const unsigned short* yr = ylow + ((size_t)(16 * w + c) * Tt + t) * Hh + q * 8;
        s8 yb[16];
#pragma unroll
        for (int kc = 0; kc < 16; ++kc) yb[kc] = *(const s8*)(yr + kc * 32);
#pragma unroll
        for (int tt = 0; tt < 8; ++tt) {
#pragma unroll
          for (int kc = 0; kc < 16; ++kc) {
            int byt = (((tt * 16 + c) * 512 + kc * 32 + q * 8) * 2) ^ aswz;
            s8 wa = *(const s8*)((const char*)Wlds + byt);
            acc[tt] = __builtin_amdgcn_mfma_f32_16x16x32_bf16(wa, yb[kc], acc[tt], 0, 0, 0);
          }
        }
      }
      u64* slot = (u64*)(ringbase + (size_t)(t & (RD - 1)) * 2048 + lane * 32);
#pragma unroll
      for (int tt = 0; tt < 8; ++tt) {
        union { f4 v; u64 u[2]; } cv; cv.v = acc[tt];
        __hip_atomic_store(slot + tt * 2, cv.u[0], __ATOMIC_RELAXED, __HIP_MEMORY_SCOPE_AGENT);
        __hip_atomic_store(slot + tt * 2 + 1, cv.u[1], __ATOMIC_RELAXED, __HIP_MEMORY_SCOPE_AGENT);
      }
      asm volatile("s_waitcnt vmcnt(0)" ::: "memory");
      if (lane == 0)
        __hip_atomic_store(myxgfl, (unsigned)(t + 1), __ATOMIC_RELAXED, __HIP_MEMORY_SCOPE_AGENT);
    }
  }
}

// out^T-tiled FC: D[c,b] += fc_w[c,k] * y2[b,k]; 32 c-tiles x 32 k-chunks, atomic f32 adds.
__launch_bounds__(256)
__global__ void fc_kernel(const float* __restrict__ w, const unsigned short* __restrict__ y2,
                          float* __restrict__ out) {
  const int ct = blockIdx.x & 31;
  const int kch = blockIdx.x >> 5;
  const int tid = threadIdx.x, lane = tid & 63, wvv = tid >> 6;
  const int b = wvv * 16 + (lane & 15);
  const int KT = Tt * Hh;  // 131072
  const int kbase = kch * 4096 + (lane >> 4) * 8;
  const int c0 = ct * 32 + (lane & 15);
  const int c1 = c0 + 16;
  const bool v0 = (c0 < Cc), v1 = (c1 < Cc);
  const float* w0 = w + (size_t)c0 * KT;
  const float* w1 = w + (size_t)c1 * KT;
  const unsigned short* yr = y2 + (size_t)b * KT;
  f4 a0 = {0.f, 0.f, 0.f, 0.f}, a1 = {0.f, 0.f, 0.f, 0.f};
  for (int kk = 0; kk < 4096; kk += 32) {
    const int k = kbase + kk;
    s8 bf = *(const s8*)(yr + k);
    s8 wa0 = {0, 0, 0, 0, 0, 0, 0, 0}, wa1 = {0, 0, 0, 0, 0, 0, 0, 0};
    if (v0) {
#pragma unroll
      for (int qq = 0; qq < 8; ++qq) wa0[qq] = (short)f2bf(w0[k + qq]);
    }
    if (v1) {
#pragma unroll
      for (int qq = 0; qq < 8; ++qq) wa1[qq] = (short)f2bf(w1[k + qq]);
    }
    a0 = __builtin_amdgcn_mfma_f32_16x16x32_bf16(wa0, bf, a0, 0, 0, 0);
    a1 = __builtin_amdgcn_mfma_f32_16x16x32_bf16(wa1, bf, a1, 0, 0, 0);
  }
  const int rr = (lane >> 4) * 4;
#pragma unroll
  for (int qq = 0; qq < 4; ++qq) {
    int ca = ct * 32 + rr + qq;
    if (ca < Cc) atomicAdd(out + (size_t)b * Cc + ca, a0[qq]);
    int cb2 = ca + 16;
    if (cb2 < Cc) atomicAdd(out + (size_t)b * Cc + cb2, a1[qq]);
  }
}

extern "C" void kernel_launch(void* const* d_in, const int* in_sizes, int n_in,
                              void* d_out, int out_size, void* d_ws, size_t ws_size,
                              hipStream_t stream) {
  P2 p;
  p.x = (const float*)d_in[0];
  p.Wih[0] = (const float*)d_in[1];  p.Whh[0] = (const float*)d_in[2];
  p.bih[0] = (const float*)d_in[3];  p.bhh[0] = (const float*)d_in[4];
  p.Wih[1] = (const float*)d_in[5];  p.Whh[1] = (const float*)d_in[6];
  p.bih[1] = (const float*)d_in[7];  p.bhh[1] = (const float*)d_in[8];
  p.Wih[2] = (const float*)d_in[9];  p.Whh[2] = (const float*)d_in[10];
  p.bih[2] = (const float*)d_in[11]; p.bhh[2] = (const float*)d_in[12];
  const float* fcw = (const float*)d_in[13];
  const float* fcb = (const float*)d_in[14];

  char* ws = (char*)d_ws;
  const size_t ysz = (size_t)Bb * Tt * Hh;  // elems per y buffer (bf16)
  p.hfl = (unsigned*)ws;
  p.xgfl = p.hfl + 192;
  unsigned short* y0 = (unsigned short*)(ws + 4096);
  p.y[0] = y0;
  p.y[1] = y0 + ysz;
  p.y[2] = y0 + 2 * ysz;
  p.ring = (float*)(ws + 4096 + 3 * ysz * 2);  // 6.3 MB

  zero_flags<<<1, 256, 0, stream>>>(p.hfl);
  bias_init_kernel<<<250, 256, 0, stream>>>(fcb, (float*)d_out);
  lstm_kernel<<<96, 256, 0, stream>>>(p);
  fc_kernel<<<1024, 256, 0, stream>>>(fcw, p.y[2], (float*)d_out);
}

// Round 4
// 2379.327 us; speedup vs baseline: 1.6853x; 1.6853x over previous
//
#include <hip/hip_runtime.h>
#include <hip/hip_bf16.h>

#define Bb 64
#define Tt 256
#define Ii 256
#define Hh 512
#define Cc 1000
#define NS 32  // blocks per layer
#define ND 16  // h dims per block

typedef float f4 __attribute__((ext_vector_type(4)));
typedef short s8 __attribute__((ext_vector_type(8)));
typedef unsigned long long u64;

__device__ __forceinline__ unsigned short f2bf(float f) {
  union { float f; unsigned u; } v; v.f = f;
  return (unsigned short)((v.u + 0x7FFFu + ((v.u >> 16) & 1u)) >> 16);
}
__device__ __forceinline__ float sigf(float x) {
  return __builtin_amdgcn_rcpf(1.f + __expf(-x));
}
__device__ __forceinline__ float tanhs(float x) {
  float ax = fabsf(x);
  float e = __expf(-2.f * ax);
  float r = (1.f - e) * __builtin_amdgcn_rcpf(1.f + e);
  return copysignf(r, x);
}

struct P3 {
  const float* x;
  const float* Whh[3]; const float* Wih[3];
  const float* bih[3]; const float* bhh[3];
  unsigned short* y[3];
  unsigned* fl;  // [3][NS][4 waves] monotonic counters, one 64B line each
};

__global__ void zero_flags(unsigned* f) {
  for (int i = threadIdx.x; i < 3 * NS * 4 * 16; i += 256) f[i] = 0;
}

__global__ void bias_init_kernel(const float* __restrict__ fcb, float* __restrict__ out) {
  int i = blockIdx.x * 256 + threadIdx.x;
  if (i < Bb * Cc) out[i] = fcb[i % Cc];
}

// 96 blocks = 3 layers x 32 n-slices (16 dims each). Fused input+recurrent GEMM.
// Per-wave chains: wave w owns batches [16w,16w+16); no intra-block barriers in loop.
// LDS row r (= tt*16 + rho) holds gate-row j = (rho&3)*H + n0 + 4*(rho>>2) + tt, so
// lane (q,c)'s 4 cells are n = n0+4q+{0..3} (contiguous u64 h store), gates = acc[tt][0..3].
__launch_bounds__(256, 1)
__global__ void lstm_kernel(P3 p) {
  const int bid = blockIdx.x;
  const int L = bid >> 5;
  const int s = bid & 31;
  const int n0 = s * ND;
  const int tid = threadIdx.x;
  const int lane = tid & 63;
  const int w = tid >> 6;
  const int q = lane >> 4;
  const int c = lane & 15;

  __shared__ unsigned short Wh[64 * 512];  // 64 KB
  __shared__ unsigned short Wi[64 * 512];  // 64 KB (L0 uses 64x256)

  const int Kin = (L == 0) ? Ii : Hh;
  {  // stage Whh slice (64 rows x 512), fp32->bf16, XOR-swizzle ((r&7)<<4)
    const float* src = p.Whh[L];
    for (int idx = tid; idx < 64 * 64; idx += 256) {
      int r = idx >> 6, kk = (idx & 63) << 3;
      int rho = r & 15, tt = r >> 4;
      int j = (rho & 3) * Hh + n0 + 4 * (rho >> 2) + tt;
      const float* sr = src + (size_t)j * Hh + kk;
      s8 tv;
#pragma unroll
      for (int e = 0; e < 8; ++e) tv[e] = (short)f2bf(sr[e]);
      int byt = ((r * 512 + kk) * 2) ^ ((r & 7) << 4);
      *(s8*)((char*)Wh + byt) = tv;
    }
    const float* si = p.Wih[L];
    const int kd8 = Kin >> 3;
    for (int idx = tid; idx < 64 * kd8; idx += 256) {
      int r = idx / kd8, kk = (idx - r * kd8) << 3;
      int rho = r & 15, tt = r >> 4;
      int j = (rho & 3) * Hh + n0 + 4 * (rho >> 2) + tt;
      const float* sr = si + (size_t)j * Kin + kk;
      s8 tv;
#pragma unroll
      for (int e = 0; e < 8; ++e) tv[e] = (short)f2bf(sr[e]);
      int byt = ((r * Kin + kk) * 2) ^ ((r & 7) << 4);
      *(s8*)((char*)Wi + byt) = tv;
    }
  }

  f4 bias[4];
#pragma unroll
  for (int tt = 0; tt < 4; ++tt)
#pragma unroll
    for (int g = 0; g < 4; ++g) {
      int bi = g * Hh + n0 + 4 * q + tt;
      bias[tt][g] = p.bih[L][bi] + p.bhh[L][bi];
    }
  float cst[4] = {0.f, 0.f, 0.f, 0.f};
  __syncthreads();

  const int aswz = (c & 7) << 4;
  unsigned short* yl = p.y[L];
  const unsigned short* ylow = (L > 0) ? p.y[L - 1] : (const unsigned short*)0;
  unsigned* myflag = p.fl + (((L * NS) + s) * 4 + w) * 16;
  const int b = 16 * w + c;

  for (int t = 0; t < Tt; ++t) {
    if (L > 0) {  // wait: y[L-1][t] from all 32 lower blocks (this wave index)
      bool ok;
      do {
        unsigned v = 0xFFFFFFFFu;
        if (lane >= 32)
          v = __hip_atomic_load(p.fl + ((((L - 1) * NS) + (lane - 32)) * 4 + w) * 16,
                                __ATOMIC_RELAXED, __HIP_MEMORY_SCOPE_AGENT);
        ok = __all(v >= (unsigned)(t + 1));
        if (!ok) __builtin_amdgcn_s_sleep(1);
      } while (!ok);
      asm volatile("" ::: "memory");
    }

    f4 acc[4];
#pragma unroll
    for (int tt = 0; tt < 4; ++tt) acc[tt] = bias[tt];

    // input GEMM (overlaps own-layer producers' tail)
    if (L == 0) {
      const float* xr = p.x + ((size_t)b * Tt + t) * Ii + 8 * q;
#pragma unroll
      for (int kc = 0; kc < 8; ++kc) {
        f4 xa = *(const f4*)(xr + kc * 32);
        f4 xc = *(const f4*)(xr + kc * 32 + 4);
        s8 xb;
#pragma unroll
        for (int e = 0; e < 4; ++e) { xb[e] = (short)f2bf(xa[e]); xb[e + 4] = (short)f2bf(xc[e]); }
#pragma unroll
        for (int tt = 0; tt < 4; ++tt) {
          int byt = (((tt * 16 + c) * 256 + kc * 32 + 8 * q) * 2) ^ aswz;
          s8 wa = *(const s8*)((const char*)Wi + byt);
          acc[tt] = __builtin_amdgcn_mfma_f32_16x16x32_bf16(wa, xb, acc[tt], 0, 0, 0);
        }
      }
    } else {
      const unsigned short* yr = ylow + ((size_t)b * Tt + t) * Hh + 8 * q;
      s8 yb[16];
#pragma unroll
      for (int kc = 0; kc < 16; ++kc) yb[kc] = *(const s8*)(yr + kc * 32);
#pragma unroll
      for (int tt = 0; tt < 4; ++tt)
#pragma unroll
        for (int kc = 0; kc < 16; ++kc) {
          int byt = (((tt * 16 + c) * 512 + kc * 32 + 8 * q) * 2) ^ aswz;
          s8 wa = *(const s8*)((const char*)Wi + byt);
          acc[tt] = __builtin_amdgcn_mfma_f32_16x16x32_bf16(wa, yb[kc], acc[tt], 0, 0, 0);
        }
    }

    if (t > 0) {  // wait: h[t-1] from all 32 same-layer blocks (this wave index)
      bool ok;
      do {
        unsigned v = 0xFFFFFFFFu;
        if (lane < 32)
          v = __hip_atomic_load(p.fl + (((L * NS) + lane) * 4 + w) * 16, __ATOMIC_RELAXED,
                                __HIP_MEMORY_SCOPE_AGENT);
        ok = __all(v >= (unsigned)t);
        if (!ok) __builtin_amdgcn_s_sleep(1);
      } while (!ok);
      asm volatile("" ::: "memory");
      const unsigned short* hr = yl + ((size_t)b * Tt + (t - 1)) * Hh + 8 * q;
      s8 hb[16];
#pragma unroll
      for (int kc = 0; kc < 16; ++kc) hb[kc] = *(const s8*)(hr + kc * 32);
#pragma unroll
      for (int tt = 0; tt < 4; ++tt)
#pragma unroll
        for (int kc = 0; kc < 16; ++kc) {
          int byt = (((tt * 16 + c) * 512 + kc * 32 + 8 * q) * 2) ^ aswz;
          s8 wa = *(const s8*)((const char*)Wh + byt);
          acc[tt] = __builtin_amdgcn_mfma_f32_16x16x32_bf16(wa, hb[kc], acc[tt], 0, 0, 0);
        }
    }

    // pointwise: cell n = n0+4q+tt, gates {i,f,g,o} = acc[tt][0..3]
    unsigned short hu[4];
#pragma unroll
    for (int tt = 0; tt < 4; ++tt) {
      float ii = sigf(acc[tt][0]), ff = sigf(acc[tt][1]);
      float gg = tanhs(acc[tt][2]), oo = sigf(acc[tt][3]);
      cst[tt] = ff * cst[tt] + ii * gg;
      hu[tt] = f2bf(oo * tanhs(cst[tt]));
    }
    u64 hv = (u64)hu[0] | ((u64)hu[1] << 16) | ((u64)hu[2] << 32) | ((u64)hu[3] << 48);
    u64* dst = (u64*)(yl + ((size_t)b * Tt + t) * Hh + n0 + 4 * q);
    __hip_atomic_store(dst, hv, __ATOMIC_RELAXED, __HIP_MEMORY_SCOPE_AGENT);
    asm volatile("s_waitcnt vmcnt(0)" ::: "memory");  // h acked at LLC
    if (lane == 0)
      __hip_atomic_store(myflag, (unsigned)(t + 1), __ATOMIC_RELAXED, __HIP_MEMORY_SCOPE_AGENT);
  }
}

// out^T-tiled FC: D[c,b] += fc_w[c,k] * y2[b,k]; 32 c-tiles x 32 k-chunks, atomic f32 adds.
__launch_bounds__(256)
__global__ void fc_kernel(const float* __restrict__ w, const unsigned short* __restrict__ y2,
                          float* __restrict__ out) {
  const int ct = blockIdx.x & 31;
  const int kch = blockIdx.x >> 5;
  const int tid = threadIdx.x, lane = tid & 63, wvv = tid >> 6;
  const int b = wvv * 16 + (lane & 15);
  const int KT = Tt * Hh;  // 131072
  const int kbase = kch * 4096 + (lane >> 4) * 8;
  const int c0 = ct * 32 + (lane & 15);
  const int c1 = c0 + 16;
  const bool v0 = (c0 < Cc), v1 = (c1 < Cc);
  const float* w0 = w + (size_t)c0 * KT;
  const float* w1 = w + (size_t)c1 * KT;
  const unsigned short* yr = y2 + (size_t)b * KT;
  f4 a0 = {0.f, 0.f, 0.f, 0.f}, a1 = {0.f, 0.f, 0.f, 0.f};
  for (int kk = 0; kk < 4096; kk += 32) {
    const int k = kbase + kk;
    s8 bf = *(const s8*)(yr + k);
    s8 wa0 = {0, 0, 0, 0, 0, 0, 0, 0}, wa1 = {0, 0, 0, 0, 0, 0, 0, 0};
    if (v0) {
#pragma unroll
      for (int qq = 0; qq < 8; ++qq) wa0[qq] = (short)f2bf(w0[k + qq]);
    }
    if (v1) {
#pragma unroll
      for (int qq = 0; qq < 8; ++qq) wa1[qq] = (short)f2bf(w1[k + qq]);
    }
    a0 = __builtin_amdgcn_mfma_f32_16x16x32_bf16(wa0, bf, a0, 0, 0, 0);
    a1 = __builtin_amdgcn_mfma_f32_16x16x32_bf16(wa1, bf, a1, 0, 0, 0);
  }
  const int rr = (lane >> 4) * 4;
#pragma unroll
  for (int qq = 0; qq < 4; ++qq) {
    int ca = ct * 32 + rr + qq;
    if (ca < Cc) atomicAdd(out + (size_t)b * Cc + ca, a0[qq]);
    int cb2 = ca + 16;
    if (cb2 < Cc) atomicAdd(out + (size_t)b * Cc + cb2, a1[qq]);
  }
}

extern "C" void kernel_launch(void* const* d_in, const int* in_sizes, int n_in,
                              void* d_out, int out_size, void* d_ws, size_t ws_size,
                              hipStream_t stream) {
  P3 p;
  p.x = (const float*)d_in[0];
  p.Wih[0] = (const float*)d_in[1];  p.Whh[0] = (const float*)d_in[2];
  p.bih[0] = (const float*)d_in[3];  p.bhh[0] = (const float*)d_in[4];
  p.Wih[1] = (const float*)d_in[5];  p.Whh[1] = (const float*)d_in[6];
  p.bih[1] = (const float*)d_in[7];  p.bhh[1] = (const float*)d_in[8];
  p.Wih[2] = (const float*)d_in[9];  p.Whh[2] = (const float*)d_in[10];
  p.bih[2] = (const float*)d_in[11]; p.bhh[2] = (const float*)d_in[12];
  const float* fcw = (const float*)d_in[13];
  const float* fcb = (const float*)d_in[14];

  char* ws = (char*)d_ws;
  p.fl = (unsigned*)ws;  // 24 KB of spread flag lines
  unsigned short* y0 = (unsigned short*)(ws + 32768);
  const size_t ysz = (size_t)Bb * Tt * Hh;
  p.y[0] = y0;
  p.y[1] = y0 + ysz;
  p.y[2] = y0 + 2 * ysz;

  zero_flags<<<1, 256, 0, stream>>>(p.fl);
  bias_init_kernel<<<250, 256, 0, stream>>>(fcb, (float*)d_out);
  lstm_kernel<<<96, 256, 0, stream>>>(p);
  fc_kernel<<<1024, 256, 0, stream>>>(fcw, p.y[2], (float*)d_out);
}